// Round 2
// baseline (685.056 us; speedup 1.0000x reference)
//
#include <hip/hip_runtime.h>
#include <hip/hip_bf16.h>
#include <stdint.h>

// Problem dims (fixed by reference)
#define TOKENS 8192
#define DIN    4096
#define DOUT   4096

typedef short bf16x8 __attribute__((ext_vector_type(8)));  // 8 bf16 = 4 VGPRs
typedef float f32x4  __attribute__((ext_vector_type(4)));  // MFMA 16x16 accum

// ---- fp32 -> bf16 round-to-nearest-even (inputs finite) ----
__device__ __forceinline__ unsigned short f2bf(float f) {
    union { float f; unsigned int u; } v; v.f = f;
    return (unsigned short)((v.u + 0x7fffu + ((v.u >> 16) & 1u)) >> 16);
}

// ---- async global->LDS, 16B/lane; LDS dest = wave-uniform base + lane*16 ----
__device__ __forceinline__ void gload_lds16(const unsigned short* g, unsigned short* l) {
    __builtin_amdgcn_global_load_lds(
        (const __attribute__((address_space(1))) unsigned int*)g,
        (__attribute__((address_space(3))) unsigned int*)l,
        16, 0, 0);
}

// ================= prologue 1: x fp32 -> bf16 =================
__global__ void cvt_x_kernel(const float* __restrict__ x,
                             unsigned short* __restrict__ xb, int n4) {
    int i = blockIdx.x * blockDim.x + threadIdx.x;
    int stride = gridDim.x * blockDim.x;
    const float4* x4 = (const float4*)x;
    ushort4* o4 = (ushort4*)xb;
    for (; i < n4; i += stride) {
        float4 v = x4[i];
        ushort4 o;
        o.x = f2bf(v.x); o.y = f2bf(v.y); o.z = f2bf(v.z); o.w = f2bf(v.w);
        o4[i] = o;
    }
}

// ======= prologue 2: W int32 [K][N] -> Wt bf16 [N][K] =======
// Register-pack transpose, no LDS. Each lane owns one n-column and 64 k-rows:
// reads are wave-coalesced 256B segments (64 lanes x 1 int, consecutive n),
// writes are 128B contiguous per lane (its own [n][k0..k0+63] bf16 run).
__global__ __launch_bounds__(256) void cvt_w_kernel(const int* __restrict__ W,
                                                    unsigned short* __restrict__ Wt) {
    const int n  = blockIdx.x * 256 + threadIdx.x;
    const int k0 = blockIdx.y * 64;
    const int* src = W + (size_t)k0 * DOUT + n;
    unsigned int* dst = (unsigned int*)(Wt + (size_t)n * DIN + k0);  // 32 uints
#pragma unroll
    for (int c = 0; c < 4; ++c) {
        int w[16];
#pragma unroll
        for (int j = 0; j < 16; ++j)
            w[j] = src[(size_t)(c * 16 + j) * DOUT];
        unsigned int p[8];
#pragma unroll
        for (int j = 0; j < 8; ++j) {
            unsigned int lo = f2bf((float)w[2 * j]);
            unsigned int hi = f2bf((float)w[2 * j + 1]);
            p[j] = lo | (hi << 16);
        }
        uint4* d4 = (uint4*)(dst + c * 8);
        d4[0] = make_uint4(p[0], p[1], p[2], p[3]);
        d4[1] = make_uint4(p[4], p[5], p[6], p[7]);
    }
}

// ================= main GEMM: C[M][N] = A[M][K] * Bt[N][K]^T =================
// m97 structure: 128x128 tile, BK=32, 4 waves 2x2, each wave 4x4 of 16x16x32 MFMA.
// XOR-swizzled LDS layout: within each 16-row/1KB staged chunk, the 16B unit for
// (row r, k-quad q) lives at physical slot (q ^ ((r>>2)&3)). Staging lane l
// therefore fetches global quad qg = (l&3) ^ ((l>>4)&3) of row l>>2 (same 64B
// row-run, just permuted -> coalescing unchanged); fragment reads apply the
// same XOR. This turns the 8-way bank conflict of the naive layout (row
// stride 64B -> bank group 16*(r&1)+4q) into 2-way (free per m136).
#define BM 128
#define BN 128
#define BK 32

__global__ __launch_bounds__(256) void gemm_bt(
    const unsigned short* __restrict__ A,   // [M][K] bf16
    const unsigned short* __restrict__ B,   // [N][K] bf16 (W transposed)
    float* __restrict__ C) {                // [M][N] fp32
    const int K = DIN, N = DOUT;

    __shared__ __align__(16) unsigned short sA[BM * BK];  // 8 KB
    __shared__ __align__(16) unsigned short sB[BN * BK];  // 8 KB

    const int wave = threadIdx.x >> 6;
    const int lane = threadIdx.x & 63;
    const int waveM = (wave >> 1) * 64;
    const int waveN = (wave & 1) * 64;

    const unsigned short* Ablk = A + (size_t)(blockIdx.y * BM) * K;
    const unsigned short* Bblk = B + (size_t)(blockIdx.x * BN) * K;

    // staging: each wave owns two 1KB chunks (16 rows x 64B) of sA and sB
    const int c0   = wave * 2;
    const int m16  = lane >> 2;                         // row within chunk
    const int qsw  = (lane & 3) ^ ((lane >> 4) & 3);    // swizzled k-quad
    const int srow = c0 * 16 + m16;
    const int kofs = qsw * 8;                           // bf16 elems
    const unsigned short* gA0 = Ablk + (size_t)srow * K + kofs;
    const unsigned short* gA1 = gA0 + (size_t)16 * K;
    const unsigned short* gB0 = Bblk + (size_t)srow * K + kofs;
    const unsigned short* gB1 = gB0 + (size_t)16 * K;
    unsigned short* lA0 = &sA[c0 * 512 + lane * 8];
    unsigned short* lA1 = &sA[(c0 + 1) * 512 + lane * 8];
    unsigned short* lB0 = &sB[c0 * 512 + lane * 8];
    unsigned short* lB1 = &sB[(c0 + 1) * 512 + lane * 8];

    // fragment read indices (A-op layout: lane -> [m=lane&15][k=(lane>>4)*8+j]);
    // physical offset of logical quad q at row r: (q ^ ((r>>2)&3))*8
    const int mrow = lane & 15;
    const int fq   = (((lane >> 4) ^ (mrow >> 2)) & 3) * 8;

    f32x4 acc[4][4];
#pragma unroll
    for (int i = 0; i < 4; ++i)
#pragma unroll
        for (int j = 0; j < 4; ++j) {
            f32x4 z = {0.f, 0.f, 0.f, 0.f};
            acc[i][j] = z;
        }

    for (int kt = 0; kt < K; kt += BK) {
        __syncthreads();                      // prior reads done before overwrite
        gload_lds16(gA0 + kt, lA0 - lane * 8 + 0);  // base is wave-uniform
        gload_lds16(gA1 + kt, lA1 - lane * 8 + 0);
        gload_lds16(gB0 + kt, lB0 - lane * 8 + 0);
        gload_lds16(gB1 + kt, lB1 - lane * 8 + 0);
        __syncthreads();                      // drains vmcnt(0): staging visible

        bf16x8 af[4], bfr[4];
#pragma unroll
        for (int mi = 0; mi < 4; ++mi)
            af[mi] = *(const bf16x8*)&sA[(waveM + mi * 16 + mrow) * BK + fq];
#pragma unroll
        for (int ni = 0; ni < 4; ++ni)
            bfr[ni] = *(const bf16x8*)&sB[(waveN + ni * 16 + mrow) * BK + fq];

#pragma unroll
        for (int mi = 0; mi < 4; ++mi)
#pragma unroll
            for (int ni = 0; ni < 4; ++ni)
                acc[mi][ni] = __builtin_amdgcn_mfma_f32_16x16x32_bf16(
                    af[mi], bfr[ni], acc[mi][ni], 0, 0, 0);
    }

    // epilogue: C/D layout col=lane&15, row=(lane>>4)*4+reg
    float* Cw = C + (size_t)(blockIdx.y * BM + waveM + (lane >> 4) * 4) * N
                + (size_t)(blockIdx.x * BN + waveN + (lane & 15));
#pragma unroll
    for (int mi = 0; mi < 4; ++mi)
#pragma unroll
        for (int ni = 0; ni < 4; ++ni)
#pragma unroll
            for (int r = 0; r < 4; ++r)
                Cw[(size_t)(mi * 16 + r) * N + ni * 16] = acc[mi][ni][r];
}

// ============ safety-net fallback if ws is too small (slow but correct) ============
__global__ void gemm_naive(const float* __restrict__ x, const int* __restrict__ W,
                           float* __restrict__ out) {
    int n = blockIdx.x * blockDim.x + threadIdx.x;
    int t = blockIdx.y;
    const float* xr = x + (size_t)t * DIN;
    float acc = 0.f;
    for (int k = 0; k < DIN; ++k)
        acc += xr[k] * (float)W[(size_t)k * DOUT + n];
    out[(size_t)t * DOUT + n] = acc;
}

extern "C" void kernel_launch(void* const* d_in, const int* in_sizes, int n_in,
                              void* d_out, int out_size, void* d_ws, size_t ws_size,
                              hipStream_t stream) {
    const float* x = (const float*)d_in[0];
    const int*   W = (const int*)d_in[1];
    float* out = (float*)d_out;

    const size_t xb_elems = (size_t)TOKENS * DIN;           // 64 MB bf16
    const size_t wt_elems = (size_t)DIN * DOUT;             // 32 MB bf16
    const size_t need = (xb_elems + wt_elems) * sizeof(unsigned short);

    if (ws_size < need) {   // should not happen; correctness safety net
        dim3 g(DOUT / 256, TOKENS);
        gemm_naive<<<g, 256, 0, stream>>>(x, W, out);
        return;
    }

    unsigned short* xb = (unsigned short*)d_ws;
    unsigned short* Wt = xb + xb_elems;

    cvt_x_kernel<<<2048, 256, 0, stream>>>(x, xb, (int)(xb_elems / 4));
    cvt_w_kernel<<<dim3(DOUT / 256, DIN / 64), 256, 0, stream>>>(W, Wt);

    dim3 grid(DOUT / BN, TOKENS / BM);   // (32, 64)
    gemm_bt<<<grid, 256, 0, stream>>>(xb, Wt, out);
}

// Round 3
// 644.781 us; speedup vs baseline: 1.0625x; 1.0625x over previous
//
#include <hip/hip_runtime.h>
#include <hip/hip_bf16.h>
#include <stdint.h>

// Problem dims (fixed by reference)
#define TOKENS 8192
#define DIN    4096
#define DOUT   4096

typedef short bf16x8 __attribute__((ext_vector_type(8)));  // 8 bf16 = 4 VGPRs
typedef float f32x4  __attribute__((ext_vector_type(4)));  // MFMA 16x16 accum

// ---- fp32 -> bf16 round-to-nearest-even (inputs finite) ----
__device__ __forceinline__ unsigned short f2bf(float f) {
    union { float f; unsigned int u; } v; v.f = f;
    return (unsigned short)((v.u + 0x7fffu + ((v.u >> 16) & 1u)) >> 16);
}

// ---- async global->LDS, 16B/lane; LDS dest = wave-uniform base + lane*16 ----
__device__ __forceinline__ void gload_lds16(const unsigned short* g, unsigned short* l) {
    __builtin_amdgcn_global_load_lds(
        (const __attribute__((address_space(1))) unsigned int*)g,
        (__attribute__((address_space(3))) unsigned int*)l,
        16, 0, 0);
}

// ================= fused prologue: one kernel, two jobs =================
// blocks [0, 1024):   W int32 [K][N] -> Wt bf16 [N][K], 256k x 64n LDS tiles.
//   reads : 256B-coalesced int4 runs per 16 lanes
//   writes: 64B-coalesced uint4 runs per 4 lanes (512B per n-row per tile)
// blocks [1024, 3072): x fp32 -> bf16, 2x float4 in -> 1x 16B store out.
#define WBLKS 1024
#define XBLKS 2048

__global__ __launch_bounds__(256) void fused_cvt(
    const float* __restrict__ x, const int* __restrict__ W,
    unsigned short* __restrict__ xb, unsigned short* __restrict__ Wt) {
    __shared__ unsigned short lds[64][264];   // [n_local][k_local], pitch 264 (33x16B)
    const int t = threadIdx.x;

    if (blockIdx.x < WBLKS) {
        // ---- W transpose part: tile k0..k0+255, n0..n0+63 ----
        const int b  = blockIdx.x;
        const int k0 = (b >> 6) * 256;        // 16 k-tiles
        const int n0 = (b & 63) * 64;         // 64 n-tiles
        const int nl = 4 * (t & 15);          // n_local base this thread fills
#pragma unroll
        for (int it = 0; it < 16; ++it) {
            const int r = (t >> 4) + 16 * it; // k_local
            int4 v = *(const int4*)&W[(size_t)(k0 + r) * DOUT + n0 + nl];
            lds[nl + 0][r] = f2bf((float)v.x);
            lds[nl + 1][r] = f2bf((float)v.y);
            lds[nl + 2][r] = f2bf((float)v.z);
            lds[nl + 3][r] = f2bf((float)v.w);
        }
        __syncthreads();
        const int n = t >> 2;                 // 0..63
        const int s = t & 3;
        unsigned short* drow = Wt + (size_t)(n0 + n) * DIN + k0;
#pragma unroll
        for (int u = 0; u < 8; ++u) {
            const int k = u * 32 + s * 8;     // lanes 0-3 cover 64B contiguous
            *(uint4*)&drow[k] = *(const uint4*)&lds[n][k];
        }
    } else {
        // ---- x convert part: 8 chunks of 8 floats per thread ----
        const int b2 = blockIdx.x - WBLKS;    // 0..2047
        const int stride = XBLKS * 256;       // chunks per sweep
        int c = b2 * 256 + t;
        const float4* x4 = (const float4*)x;
        uint4* o = (uint4*)xb;                // 8 bf16 = 16B per chunk
#pragma unroll
        for (int j = 0; j < 8; ++j, c += stride) {
            float4 a = x4[2 * c];
            float4 bvec = x4[2 * c + 1];
            uint4 p;
            p.x = (unsigned)f2bf(a.x)    | ((unsigned)f2bf(a.y) << 16);
            p.y = (unsigned)f2bf(a.z)    | ((unsigned)f2bf(a.w) << 16);
            p.z = (unsigned)f2bf(bvec.x) | ((unsigned)f2bf(bvec.y) << 16);
            p.w = (unsigned)f2bf(bvec.z) | ((unsigned)f2bf(bvec.w) << 16);
            o[c] = p;
        }
    }
}

// ================= main GEMM: C[M][N] = A[M][K] * Bt[N][K]^T =================
// m97 structure: 128x128 tile, BK=32, 4 waves 2x2, each wave 4x4 of 16x16x32 MFMA.
// XOR-swizzled LDS k-quads (neutral on conflicts per R2 measurement; kept).
#define BM 128
#define BN 128
#define BK 32

__global__ __launch_bounds__(256) void gemm_bt(
    const unsigned short* __restrict__ A,   // [M][K] bf16
    const unsigned short* __restrict__ B,   // [N][K] bf16 (W transposed)
    float* __restrict__ C) {                // [M][N] fp32
    const int K = DIN, N = DOUT;

    __shared__ __align__(16) unsigned short sA[BM * BK];  // 8 KB
    __shared__ __align__(16) unsigned short sB[BN * BK];  // 8 KB

    const int wave = threadIdx.x >> 6;
    const int lane = threadIdx.x & 63;
    const int waveM = (wave >> 1) * 64;
    const int waveN = (wave & 1) * 64;

    const unsigned short* Ablk = A + (size_t)(blockIdx.y * BM) * K;
    const unsigned short* Bblk = B + (size_t)(blockIdx.x * BN) * K;

    // staging: each wave owns two 1KB chunks (16 rows x 64B) of sA and sB
    const int c0   = wave * 2;
    const int m16  = lane >> 2;                         // row within chunk
    const int qsw  = (lane & 3) ^ ((lane >> 4) & 3);    // swizzled k-quad
    const int srow = c0 * 16 + m16;
    const int kofs = qsw * 8;                           // bf16 elems
    const unsigned short* gA0 = Ablk + (size_t)srow * K + kofs;
    const unsigned short* gA1 = gA0 + (size_t)16 * K;
    const unsigned short* gB0 = Bblk + (size_t)srow * K + kofs;
    const unsigned short* gB1 = gB0 + (size_t)16 * K;
    unsigned short* lA0 = &sA[c0 * 512];
    unsigned short* lA1 = &sA[(c0 + 1) * 512];
    unsigned short* lB0 = &sB[c0 * 512];
    unsigned short* lB1 = &sB[(c0 + 1) * 512];

    // fragment reads: logical quad q=(lane>>4) at row r lives at slot q^((r>>2)&3)
    const int mrow = lane & 15;
    const int fq   = (((lane >> 4) ^ (mrow >> 2)) & 3) * 8;

    f32x4 acc[4][4];
#pragma unroll
    for (int i = 0; i < 4; ++i)
#pragma unroll
        for (int j = 0; j < 4; ++j) {
            f32x4 z = {0.f, 0.f, 0.f, 0.f};
            acc[i][j] = z;
        }

    for (int kt = 0; kt < K; kt += BK) {
        __syncthreads();                      // prior reads done before overwrite
        gload_lds16(gA0 + kt, lA0);
        gload_lds16(gA1 + kt, lA1);
        gload_lds16(gB0 + kt, lB0);
        gload_lds16(gB1 + kt, lB1);
        __syncthreads();                      // drains vmcnt(0): staging visible

        bf16x8 af[4], bfr[4];
#pragma unroll
        for (int mi = 0; mi < 4; ++mi)
            af[mi] = *(const bf16x8*)&sA[(waveM + mi * 16 + mrow) * BK + fq];
#pragma unroll
        for (int ni = 0; ni < 4; ++ni)
            bfr[ni] = *(const bf16x8*)&sB[(waveN + ni * 16 + mrow) * BK + fq];

#pragma unroll
        for (int mi = 0; mi < 4; ++mi)
#pragma unroll
            for (int ni = 0; ni < 4; ++ni)
                acc[mi][ni] = __builtin_amdgcn_mfma_f32_16x16x32_bf16(
                    af[mi], bfr[ni], acc[mi][ni], 0, 0, 0);
    }

    // epilogue: C/D layout col=lane&15, row=(lane>>4)*4+reg
    float* Cw = C + (size_t)(blockIdx.y * BM + waveM + (lane >> 4) * 4) * N
                + (size_t)(blockIdx.x * BN + waveN + (lane & 15));
#pragma unroll
    for (int mi = 0; mi < 4; ++mi)
#pragma unroll
        for (int ni = 0; ni < 4; ++ni)
#pragma unroll
            for (int r = 0; r < 4; ++r)
                Cw[(size_t)(mi * 16 + r) * N + ni * 16] = acc[mi][ni][r];
}

// ============ safety-net fallback if ws is too small (slow but correct) ============
__global__ void gemm_naive(const float* __restrict__ x, const int* __restrict__ W,
                           float* __restrict__ out) {
    int n = blockIdx.x * blockDim.x + threadIdx.x;
    int t = blockIdx.y;
    const float* xr = x + (size_t)t * DIN;
    float acc = 0.f;
    for (int k = 0; k < DIN; ++k)
        acc += xr[k] * (float)W[(size_t)k * DOUT + n];
    out[(size_t)t * DOUT + n] = acc;
}

extern "C" void kernel_launch(void* const* d_in, const int* in_sizes, int n_in,
                              void* d_out, int out_size, void* d_ws, size_t ws_size,
                              hipStream_t stream) {
    const float* x = (const float*)d_in[0];
    const int*   W = (const int*)d_in[1];
    float* out = (float*)d_out;

    const size_t xb_elems = (size_t)TOKENS * DIN;           // 64 MB bf16
    const size_t wt_elems = (size_t)DIN * DOUT;             // 32 MB bf16
    const size_t need = (xb_elems + wt_elems) * sizeof(unsigned short);

    if (ws_size < need) {   // should not happen; correctness safety net
        dim3 g(DOUT / 256, TOKENS);
        gemm_naive<<<g, 256, 0, stream>>>(x, W, out);
        return;
    }

    unsigned short* xb = (unsigned short*)d_ws;
    unsigned short* Wt = xb + xb_elems;

    fused_cvt<<<WBLKS + XBLKS, 256, 0, stream>>>(x, W, xb, Wt);

    dim3 grid(DOUT / BN, TOKENS / BM);   // (32, 64)
    gemm_bt<<<grid, 256, 0, stream>>>(xb, Wt, out);
}